// Round 6
// baseline (248.764 us; speedup 1.0000x reference)
//
#include <hip/hip_runtime.h>
#include <math.h>

#define NB 32            // batch
#define DET_BLOCKS 96    // 3 scales * 32 images
#define SEG_BLOCKS 1024  // 32 chunks/image: 32KB mask (regs) + 4x32KB logits
#define TOTAL_BLOCKS (DET_BLOCKS + SEG_BLOCKS)

typedef float floatx4 __attribute__((ext_vector_type(4)));
typedef int   intx4   __attribute__((ext_vector_type(4)));

// ---------- math helpers (match reference semantics) ----------

__device__ __forceinline__ float bce_logits(float x, float y) {
    // max(x,0) - x*y + log1p(exp(-|x|))
    float a = fabsf(x);
    return fmaxf(x, 0.f) - x * y + __logf(1.f + __expf(-a));
}

__device__ __forceinline__ float focal_elt(float x, float t) {
    // t is exactly 0.0 or 1.0 (one-hot)
    float p = 1.f / (1.f + __expf(-x));
    float ce = bce_logits(x, t);
    float p_t = (t > 0.5f) ? p : (1.f - p);
    float a_t = (t > 0.5f) ? 0.25f : 0.75f;
    float om = 1.f - p_t;
    return a_t * om * om * ce;
}

// Block reduction for N floats, blockDim.x == 256 (4 waves of 64).
template <int N>
__device__ void blk_reduce_arr(float* v) {
    __shared__ float sm[N][4];
    int lane = threadIdx.x & 63;
    int wid  = threadIdx.x >> 6;
#pragma unroll
    for (int j = 0; j < N; j++) {
        float x = v[j];
#pragma unroll
        for (int off = 32; off > 0; off >>= 1) x += __shfl_down(x, off, 64);
        if (lane == 0) sm[j][wid] = x;
    }
    __syncthreads();
    if (threadIdx.x == 0) {
#pragma unroll
        for (int j = 0; j < N; j++) {
            float s = 0.f;
#pragma unroll
            for (int w = 0; w < 4; w++) s += sm[j][w];
            v[j] = s;
        }
    }
}

// ---------- fused: det (blocks 0..95) + seg mask-in-regs (blocks 96..) ----------

__global__ __launch_bounds__(256) void fused_kernel(
        const float* __restrict__ seg_logits, const int* __restrict__ mask,
        const float* __restrict__ cls0, const float* __restrict__ cls1, const float* __restrict__ cls2,
        const float* __restrict__ reg0, const float* __restrict__ reg1, const float* __restrict__ reg2,
        const float* __restrict__ cen0, const float* __restrict__ cen1, const float* __restrict__ cen2,
        const float* __restrict__ boxes, const int* __restrict__ labels,
        float* __restrict__ segpart, float* __restrict__ detc) {

    if (blockIdx.x < DET_BLOCKS) {
        // ===== det block: one (scale, image) =====
        const int s = blockIdx.x >> 5;   // 0..2
        const int b = blockIdx.x & 31;   // 0..31
        int Wd, shift, L; float stride;
        const float *cls, *reg, *cen;
        if (s == 0)      { Wd = 64; shift = 6; L = 4096; stride = 8.f;  cls = cls0; reg = reg0; cen = cen0; }
        else if (s == 1) { Wd = 32; shift = 5; L = 1024; stride = 16.f; cls = cls1; reg = reg1; cen = cen1; }
        else             { Wd = 16; shift = 4; L = 256;  stride = 32.f; cls = cls2; reg = reg2; cen = cen2; }

        __shared__ float sx0[20], sy0[20], sx1[20], sy1[20], sar[20];
        __shared__ int   slb[20];
        if (threadIdx.x < 20) {
            int k = threadIdx.x;
            const float* bb = boxes + (b * 20 + k) * 4;
            float cx = bb[0] * 512.f, cy = bb[1] * 512.f;
            float w  = bb[2] * 512.f, h  = bb[3] * 512.f;
            float x0 = cx - 0.5f * w, y0 = cy - 0.5f * h;
            float x1 = cx + 0.5f * w, y1 = cy + 0.5f * h;
            sx0[k] = x0; sy0[k] = y0; sx1[k] = x1; sy1[k] = y1;
            sar[k] = (x1 - x0) * (y1 - y0);
            slb[k] = labels[b * 20 + k];
        }
        __syncthreads();

        const float* clsb = cls + (size_t)b * 5 * L;
        const float* regb = reg + (size_t)b * 4 * L;
        const float* cenb = cen + (size_t)b * L;
        const float inv = 1.f / stride;

        float cls_s = 0.f, reg_s = 0.f, cen_s = 0.f, np = 0.f;
        for (int l = threadIdx.x; l < L; l += 256) {
            float lx = ((l & (Wd - 1)) + 0.5f) * stride;
            float ly = ((l >> shift)   + 0.5f) * stride;
            int bk = -1; float ba = INFINITY;
            float bl = 0.f, btp = 0.f, brr = 0.f, bbt = 0.f;
#pragma unroll
            for (int k = 0; k < 20; k++) {
                float li = lx - sx0[k], ti = ly - sy0[k];
                float ri = sx1[k] - lx, bi = sy1[k] - ly;
                float mn = fminf(fminf(li, ti), fminf(ri, bi));
                if (mn > 0.f && sar[k] < ba) {   // strict '<' == first-occurrence argmin
                    ba = sar[k]; bk = k;
                    bl = li; btp = ti; brr = ri; bbt = bi;
                }
            }
            int tl = (bk >= 0) ? slb[bk] : -1;
#pragma unroll
            for (int c = 0; c < 4; c++) {
                float x = clsb[(c + 1) * L + l];   // channel 0 dropped by reference
                cls_s += focal_elt(x, (c == tl) ? 1.f : 0.f);
            }
            if (bk >= 0) {
                float r0 = bl * inv, r1 = btp * inv, r2 = brr * inv, r3 = bbt * inv;
                float d0 = regb[0 * L + l] - r0;
                float d1 = regb[1 * L + l] - r1;
                float d2 = regb[2 * L + l] - r2;
                float d3 = regb[3 * L + l] - r3;
                float a0 = fabsf(d0), a1 = fabsf(d1), a2 = fabsf(d2), a3 = fabsf(d3);
                float sl = (a0 < 1.f ? 0.5f * d0 * d0 : a0 - 0.5f)
                         + (a1 < 1.f ? 0.5f * d1 * d1 : a1 - 0.5f)
                         + (a2 < 1.f ? 0.5f * d2 * d2 : a2 - 0.5f)
                         + (a3 < 1.f ? 0.5f * d3 * d3 : a3 - 0.5f);
                reg_s += 0.25f * sl;
                float mnlr = fminf(r0, r2), mxlr = fmaxf(r0, r2);
                float mntb = fminf(r1, r3), mxtb = fmaxf(r1, r3);
                float v = (mnlr / (mxlr + 1e-6f)) * (mntb / (mxtb + 1e-6f));
                v = fminf(fmaxf(v, 0.f), 1.f);
                float ct = sqrtf(v);
                cen_s += bce_logits(cenb[l], ct);
                np += 1.f;
            }
        }

        float v4[4] = {cls_s, reg_s, cen_s, np};
        blk_reduce_arr<4>(v4);
        if (threadIdx.x == 0) {
            float cls_l = v4[0] / (L * 4.f);
            float npos  = v4[3];
            float denom = fmaxf(npos, 1.f);
            float reg_l = (npos > 0.f) ? v4[1] / denom : 0.f;
            float cen_l = (npos > 0.f) ? v4[2] / denom : 0.f;
            detc[blockIdx.x] = (cls_l + reg_l + cen_l) * (1.f / (float)DET_BLOCKS);
        }
        return;
    }

    // ===== seg block: mask-in-registers, 4 contiguous channel sweeps =====
    // Minimum logical bytes + proven-good stream shape:
    //  - block owns one 32-KB mask chunk (2048 int4 quads) of image b and the
    //    FOUR matching 32-KB logit chunks (channels 0..3 of the same pixels).
    //  - thread t loads its 8 mask quads ONCE, converts to float ONCE (regs),
    //    then sweeps 4 channel chunks; each sweep is a single contiguous
    //    32-KB stream. No LDS, no __syncthreads, no re-reads anywhere.
    // Logical traffic = exactly 160 MB chip-wide (vs 256 MB in r4/r5 which
    // re-read the mask 4x at 3.4 TB/s service rate).
    const int s = blockIdx.x - DET_BLOCKS;   // 0..1023
    const int b = s >> 5;                    // image
    const int k = s & 31;                    // 32-KB chunk within image
    const int t = threadIdx.x;

    const intx4*   Mq = (const intx4*)mask + (size_t)b * 65536 + k * 2048;
    const floatx4* Lq = (const floatx4*)seg_logits + (size_t)b * 262144 + k * 2048;

    // mask -> registers, convert once (reused by all 4 channels)
    intx4 mr[8];
#pragma unroll
    for (int j = 0; j < 8; j++) mr[j] = Mq[j * 256 + t];
    float mf[8][4];
#pragma unroll
    for (int j = 0; j < 8; j++) {
        mf[j][0] = (float)mr[j].x; mf[j][1] = (float)mr[j].y;
        mf[j][2] = (float)mr[j].z; mf[j][3] = (float)mr[j].w;
    }

    float acc = 0.f;
#pragma unroll
    for (int c = 0; c < 4; c++) {
#pragma unroll
        for (int j = 0; j < 8; j++) {
            const floatx4 x = Lq[c * 65536 + j * 256 + t];
            acc += bce_logits(x.x, mf[j][0]) + bce_logits(x.y, mf[j][1])
                 + bce_logits(x.z, mf[j][2]) + bce_logits(x.w, mf[j][3]);
        }
    }

    float v[1] = {acc};
    blk_reduce_arr<1>(v);
    if (threadIdx.x == 0) segpart[s] = v[0];
}

// ---------- final combine: all terms pre-scaled, one accumulator ----------

__global__ __launch_bounds__(256) void final_kernel(
        const float* __restrict__ segpart, const float* __restrict__ detc,
        const float* __restrict__ cls_pred, const int* __restrict__ cls_target,
        float* __restrict__ out) {
    const float seg_scale = 1.f / 33554432.f;   // B*4*512*512 (2^-25, exact)
    const float cls_scale = 0.5f / 320.f;       // W_CLS / (B*10)
    float acc = 0.f;
    for (int i = threadIdx.x; i < SEG_BLOCKS; i += 256) acc += segpart[i] * seg_scale;
    if (threadIdx.x < DET_BLOCKS) acc += detc[threadIdx.x];
    for (int e = threadIdx.x; e < NB * 10; e += 256) {
        int i = e / 10, c = e - i * 10;
        acc += cls_scale * focal_elt(cls_pred[e], (cls_target[i] == c) ? 1.f : 0.f);
    }
    float v[1] = {acc};
    blk_reduce_arr<1>(v);
    if (threadIdx.x == 0) out[0] = v[0];
}

// ---------- launch ----------

extern "C" void kernel_launch(void* const* d_in, const int* in_sizes, int n_in,
                              void* d_out, int out_size, void* d_ws, size_t ws_size,
                              hipStream_t stream) {
    const float* seg_logits = (const float*)d_in[0];
    const int*   seg_mask   = (const int*)d_in[1];
    const float* cls0 = (const float*)d_in[2];
    const float* cls1 = (const float*)d_in[3];
    const float* cls2 = (const float*)d_in[4];
    const float* reg0 = (const float*)d_in[5];
    const float* reg1 = (const float*)d_in[6];
    const float* reg2 = (const float*)d_in[7];
    const float* cen0 = (const float*)d_in[8];
    const float* cen1 = (const float*)d_in[9];
    const float* cen2 = (const float*)d_in[10];
    const float* boxes  = (const float*)d_in[11];
    const int*   labels = (const int*)d_in[12];
    const float* cls_pred   = (const float*)d_in[13];
    const int*   cls_target = (const int*)d_in[14];

    float* ws      = (float*)d_ws;
    float* segpart = ws;                 // SEG_BLOCKS floats
    float* detc    = ws + SEG_BLOCKS;    // DET_BLOCKS floats

    fused_kernel<<<TOTAL_BLOCKS, 256, 0, stream>>>(seg_logits, seg_mask,
                                                   cls0, cls1, cls2,
                                                   reg0, reg1, reg2,
                                                   cen0, cen1, cen2,
                                                   boxes, labels, segpart, detc);
    final_kernel<<<1, 256, 0, stream>>>(segpart, detc, cls_pred, cls_target,
                                        (float*)d_out);
}

// Round 7
// 244.247 us; speedup vs baseline: 1.0185x; 1.0185x over previous
//
#include <hip/hip_runtime.h>
#include <math.h>

#define NB 32            // batch
#define DET_BLOCKS 96    // 3 scales * 32 images
#define SEG_BLOCKS 1024  // 32 chunks/image: 32KB mask (regs) + 4x32KB logits
#define TOTAL_BLOCKS (DET_BLOCKS + SEG_BLOCKS)

typedef float floatx4 __attribute__((ext_vector_type(4)));
typedef int   intx4   __attribute__((ext_vector_type(4)));

// Single packed accumulator: bits [63:44] = completion count, bits [43:0] =
// fixed-point (2^-32) sum of NON-NEGATIVE pre-scaled partials (total < 2^12,
// so the fields cannot collide). The partial travels THROUGH the atomic, so
// no __threadfence is needed anywhere (r2's per-block fences were the
// catastrophic path). Integer addition commutes exactly -> deterministic.
// Zero-initialized at module load; the finishing block resets it, so graph
// replays stay self-consistent.
__device__ unsigned long long g_slot = 0ULL;

// ---------- math helpers (match reference semantics) ----------

__device__ __forceinline__ float bce_logits(float x, float y) {
    // max(x,0) - x*y + log1p(exp(-|x|))
    float a = fabsf(x);
    return fmaxf(x, 0.f) - x * y + __logf(1.f + __expf(-a));
}

__device__ __forceinline__ float focal_elt(float x, float t) {
    // t is exactly 0.0 or 1.0 (one-hot)
    float p = 1.f / (1.f + __expf(-x));
    float ce = bce_logits(x, t);
    float p_t = (t > 0.5f) ? p : (1.f - p);
    float a_t = (t > 0.5f) ? 0.25f : 0.75f;
    float om = 1.f - p_t;
    return a_t * om * om * ce;
}

// Block reduction for N floats, blockDim.x == 256 (4 waves of 64).
template <int N>
__device__ void blk_reduce_arr(float* v) {
    __shared__ float sm[N][4];
    int lane = threadIdx.x & 63;
    int wid  = threadIdx.x >> 6;
#pragma unroll
    for (int j = 0; j < N; j++) {
        float x = v[j];
#pragma unroll
        for (int off = 32; off > 0; off >>= 1) x += __shfl_down(x, off, 64);
        if (lane == 0) sm[j][wid] = x;
    }
    __syncthreads();
    if (threadIdx.x == 0) {
#pragma unroll
        for (int j = 0; j < N; j++) {
            float s = 0.f;
#pragma unroll
            for (int w = 0; w < 4; w++) s += sm[j][w];
            v[j] = s;
        }
    }
}

// thread 0 of each block: publish this block's pre-scaled partial; the block
// that completes the count finalizes the output. No fences, one atomic.
__device__ __forceinline__ void emit_partial(float partial, float* out) {
    unsigned long long enc = (1ULL << 44) |
        (unsigned long long)llrint((double)partial * 4294967296.0);
    unsigned long long tot = atomicAdd(&g_slot, enc) + enc;
    if ((tot >> 44) == (unsigned long long)TOTAL_BLOCKS) {
        out[0] = (float)((double)(tot & ((1ULL << 44) - 1ULL)) *
                         (1.0 / 4294967296.0));
        atomicExch(&g_slot, 0ULL);   // re-arm for next launch/replay
    }
}

// ---------- single fused kernel: det + seg + packed-atomic final ----------

__global__ __launch_bounds__(256) void fused_kernel(
        const float* __restrict__ seg_logits, const int* __restrict__ mask,
        const float* __restrict__ cls0, const float* __restrict__ cls1, const float* __restrict__ cls2,
        const float* __restrict__ reg0, const float* __restrict__ reg1, const float* __restrict__ reg2,
        const float* __restrict__ cen0, const float* __restrict__ cen1, const float* __restrict__ cen2,
        const float* __restrict__ boxes, const int* __restrict__ labels,
        const float* __restrict__ cls_pred, const int* __restrict__ cls_target,
        float* __restrict__ out) {

    if (blockIdx.x < DET_BLOCKS) {
        // ===== det block: one (scale, image) =====
        const int s = blockIdx.x >> 5;   // 0..2
        const int b = blockIdx.x & 31;   // 0..31
        int Wd, shift, L; float stride;
        const float *cls, *reg, *cen;
        if (s == 0)      { Wd = 64; shift = 6; L = 4096; stride = 8.f;  cls = cls0; reg = reg0; cen = cen0; }
        else if (s == 1) { Wd = 32; shift = 5; L = 1024; stride = 16.f; cls = cls1; reg = reg1; cen = cen1; }
        else             { Wd = 16; shift = 4; L = 256;  stride = 32.f; cls = cls2; reg = reg2; cen = cen2; }

        __shared__ float sx0[20], sy0[20], sx1[20], sy1[20], sar[20];
        __shared__ int   slb[20];
        if (threadIdx.x < 20) {
            int k = threadIdx.x;
            const float* bb = boxes + (b * 20 + k) * 4;
            float cx = bb[0] * 512.f, cy = bb[1] * 512.f;
            float w  = bb[2] * 512.f, h  = bb[3] * 512.f;
            float x0 = cx - 0.5f * w, y0 = cy - 0.5f * h;
            float x1 = cx + 0.5f * w, y1 = cy + 0.5f * h;
            sx0[k] = x0; sy0[k] = y0; sx1[k] = x1; sy1[k] = y1;
            sar[k] = (x1 - x0) * (y1 - y0);
            slb[k] = labels[b * 20 + k];
        }
        __syncthreads();

        const float* clsb = cls + (size_t)b * 5 * L;
        const float* regb = reg + (size_t)b * 4 * L;
        const float* cenb = cen + (size_t)b * L;
        const float inv = 1.f / stride;

        float cls_s = 0.f, reg_s = 0.f, cen_s = 0.f, np = 0.f, clsp = 0.f;
        // fold the W_CLS focal term into the lightest det blocks (s==2, L=256):
        // threads 0..9 handle image b's 10 class logits.
        if (s == 2 && threadIdx.x < 10) {
            clsp = focal_elt(cls_pred[b * 10 + threadIdx.x],
                             (cls_target[b] == (int)threadIdx.x) ? 1.f : 0.f);
        }
        for (int l = threadIdx.x; l < L; l += 256) {
            float lx = ((l & (Wd - 1)) + 0.5f) * stride;
            float ly = ((l >> shift)   + 0.5f) * stride;
            int bk = -1; float ba = INFINITY;
            float bl = 0.f, btp = 0.f, brr = 0.f, bbt = 0.f;
#pragma unroll
            for (int k = 0; k < 20; k++) {
                float li = lx - sx0[k], ti = ly - sy0[k];
                float ri = sx1[k] - lx, bi = sy1[k] - ly;
                float mn = fminf(fminf(li, ti), fminf(ri, bi));
                if (mn > 0.f && sar[k] < ba) {   // strict '<' == first-occurrence argmin
                    ba = sar[k]; bk = k;
                    bl = li; btp = ti; brr = ri; bbt = bi;
                }
            }
            int tl = (bk >= 0) ? slb[bk] : -1;
#pragma unroll
            for (int c = 0; c < 4; c++) {
                float x = clsb[(c + 1) * L + l];   // channel 0 dropped by reference
                cls_s += focal_elt(x, (c == tl) ? 1.f : 0.f);
            }
            if (bk >= 0) {
                float r0 = bl * inv, r1 = btp * inv, r2 = brr * inv, r3 = bbt * inv;
                float d0 = regb[0 * L + l] - r0;
                float d1 = regb[1 * L + l] - r1;
                float d2 = regb[2 * L + l] - r2;
                float d3 = regb[3 * L + l] - r3;
                float a0 = fabsf(d0), a1 = fabsf(d1), a2 = fabsf(d2), a3 = fabsf(d3);
                float sl = (a0 < 1.f ? 0.5f * d0 * d0 : a0 - 0.5f)
                         + (a1 < 1.f ? 0.5f * d1 * d1 : a1 - 0.5f)
                         + (a2 < 1.f ? 0.5f * d2 * d2 : a2 - 0.5f)
                         + (a3 < 1.f ? 0.5f * d3 * d3 : a3 - 0.5f);
                reg_s += 0.25f * sl;
                float mnlr = fminf(r0, r2), mxlr = fmaxf(r0, r2);
                float mntb = fminf(r1, r3), mxtb = fmaxf(r1, r3);
                float v = (mnlr / (mxlr + 1e-6f)) * (mntb / (mxtb + 1e-6f));
                v = fminf(fmaxf(v, 0.f), 1.f);
                float ct = sqrtf(v);
                cen_s += bce_logits(cenb[l], ct);
                np += 1.f;
            }
        }

        float v5[5] = {cls_s, reg_s, cen_s, np, clsp};
        blk_reduce_arr<5>(v5);
        if (threadIdx.x == 0) {
            float cls_l = v5[0] / (L * 4.f);
            float npos  = v5[3];
            float denom = fmaxf(npos, 1.f);
            float reg_l = (npos > 0.f) ? v5[1] / denom : 0.f;
            float cen_l = (npos > 0.f) ? v5[2] / denom : 0.f;
            float partial = (cls_l + reg_l + cen_l) * (1.f / (float)DET_BLOCKS)
                          + v5[4] * (0.5f / 320.f);   // W_CLS / (B*10)
            emit_partial(partial, out);
        }
        return;
    }

    // ===== seg block: mask-in-registers, 4 contiguous channel sweeps =====
    // (r6 structure: minimum logical bytes, no LDS, no syncs. The far-memory
    // read rate is pinned at ~2.1 TB/s by per-CU line-fill concurrency --
    // invariant across 7 tested structures -- so this phase is at its floor.)
    const int s = blockIdx.x - DET_BLOCKS;   // 0..1023
    const int b = s >> 5;                    // image
    const int k = s & 31;                    // 32-KB chunk within image
    const int t = threadIdx.x;

    const intx4*   Mq = (const intx4*)mask + (size_t)b * 65536 + k * 2048;
    const floatx4* Lq = (const floatx4*)seg_logits + (size_t)b * 262144 + k * 2048;

    // mask -> registers, convert once (reused by all 4 channels)
    intx4 mr[8];
#pragma unroll
    for (int j = 0; j < 8; j++) mr[j] = Mq[j * 256 + t];
    float mf[8][4];
#pragma unroll
    for (int j = 0; j < 8; j++) {
        mf[j][0] = (float)mr[j].x; mf[j][1] = (float)mr[j].y;
        mf[j][2] = (float)mr[j].z; mf[j][3] = (float)mr[j].w;
    }

    float acc = 0.f;
#pragma unroll
    for (int c = 0; c < 4; c++) {
#pragma unroll
        for (int j = 0; j < 8; j++) {
            const floatx4 x = Lq[c * 65536 + j * 256 + t];
            acc += bce_logits(x.x, mf[j][0]) + bce_logits(x.y, mf[j][1])
                 + bce_logits(x.z, mf[j][2]) + bce_logits(x.w, mf[j][3]);
        }
    }

    float v[1] = {acc};
    blk_reduce_arr<1>(v);
    if (threadIdx.x == 0) {
        emit_partial(v[0] * (1.f / 33554432.f), out);   // / B*4*512*512
    }
}

// ---------- launch: single dispatch ----------

extern "C" void kernel_launch(void* const* d_in, const int* in_sizes, int n_in,
                              void* d_out, int out_size, void* d_ws, size_t ws_size,
                              hipStream_t stream) {
    const float* seg_logits = (const float*)d_in[0];
    const int*   seg_mask   = (const int*)d_in[1];
    const float* cls0 = (const float*)d_in[2];
    const float* cls1 = (const float*)d_in[3];
    const float* cls2 = (const float*)d_in[4];
    const float* reg0 = (const float*)d_in[5];
    const float* reg1 = (const float*)d_in[6];
    const float* reg2 = (const float*)d_in[7];
    const float* cen0 = (const float*)d_in[8];
    const float* cen1 = (const float*)d_in[9];
    const float* cen2 = (const float*)d_in[10];
    const float* boxes  = (const float*)d_in[11];
    const int*   labels = (const int*)d_in[12];
    const float* cls_pred   = (const float*)d_in[13];
    const int*   cls_target = (const int*)d_in[14];

    fused_kernel<<<TOTAL_BLOCKS, 256, 0, stream>>>(seg_logits, seg_mask,
                                                   cls0, cls1, cls2,
                                                   reg0, reg1, reg2,
                                                   cen0, cen1, cen2,
                                                   boxes, labels,
                                                   cls_pred, cls_target,
                                                   (float*)d_out);
}

// Round 8
// 242.918 us; speedup vs baseline: 1.0241x; 1.0055x over previous
//
#include <hip/hip_runtime.h>
#include <math.h>

#define NB 32            // batch
#define DET_BLOCKS 96    // 3 scales * 32 images
#define SEG_BLOCKS 1024  // 32 chunks/image: 32KB mask (regs) + 4x32KB logits
#define TOTAL_BLOCKS (DET_BLOCKS + SEG_BLOCKS)   // 1120 = 8 * 140
#define SLOTS 8
#define SLOT_QUOTA (TOTAL_BLOCKS / SLOTS)        // 140, exact

typedef float floatx4 __attribute__((ext_vector_type(4)));
typedef int   intx4   __attribute__((ext_vector_type(4)));

// Hierarchical packed accumulators. Each value: bits [63:44] = completion
// count, bits [43:0] = fixed-point (2^-32) sum of NON-NEGATIVE pre-scaled
// partials (total < 2^12 -> fields cannot collide). Integer adds commute
// exactly -> deterministic, bit-identical to the r7 single-slot version.
//
// r7 lesson: ONE slot serialized ~1120 same-line cross-XCD atomics arriving
// in an end-burst (~20 ns each = ~22 us idle tail). Level 1 spreads the
// burst over 8 slots -- blockIdx&7 matches round-robin block->XCD dispatch,
// so each slot line stays in one XCD's L2 -- and each slot is PADDED TO ITS
// OWN 128-B CACHE LINE (8 u64 in one line would still bounce). Level 2 sees
// only 8 atomics. Slot/level-2 finishers re-arm the slots, so graph replays
// stay self-consistent.
__device__ unsigned long long g_slot1[SLOTS * 16];   // one u64 per 128-B line
__device__ unsigned long long g_slot2 = 0ULL;

// ---------- math helpers (match reference semantics) ----------

__device__ __forceinline__ float bce_logits(float x, float y) {
    // max(x,0) - x*y + log1p(exp(-|x|))
    float a = fabsf(x);
    return fmaxf(x, 0.f) - x * y + __logf(1.f + __expf(-a));
}

__device__ __forceinline__ float focal_elt(float x, float t) {
    // t is exactly 0.0 or 1.0 (one-hot)
    float p = 1.f / (1.f + __expf(-x));
    float ce = bce_logits(x, t);
    float p_t = (t > 0.5f) ? p : (1.f - p);
    float a_t = (t > 0.5f) ? 0.25f : 0.75f;
    float om = 1.f - p_t;
    return a_t * om * om * ce;
}

// Block reduction for N floats, blockDim.x == 256 (4 waves of 64).
template <int N>
__device__ void blk_reduce_arr(float* v) {
    __shared__ float sm[N][4];
    int lane = threadIdx.x & 63;
    int wid  = threadIdx.x >> 6;
#pragma unroll
    for (int j = 0; j < N; j++) {
        float x = v[j];
#pragma unroll
        for (int off = 32; off > 0; off >>= 1) x += __shfl_down(x, off, 64);
        if (lane == 0) sm[j][wid] = x;
    }
    __syncthreads();
    if (threadIdx.x == 0) {
#pragma unroll
        for (int j = 0; j < N; j++) {
            float s = 0.f;
#pragma unroll
            for (int w = 0; w < 4; w++) s += sm[j][w];
            v[j] = s;
        }
    }
}

// thread 0 of each block: publish this block's pre-scaled partial through the
// 2-level packed-atomic tree. No fences anywhere (data travels through the
// atomics themselves).
__device__ __forceinline__ void emit_partial(float partial, float* out) {
    const unsigned long long MASK44 = (1ULL << 44) - 1ULL;
    unsigned long long enc = (1ULL << 44) |
        (unsigned long long)llrint((double)partial * 4294967296.0);
    const int slot = (int)(blockIdx.x & (SLOTS - 1)) * 16;
    unsigned long long tot = atomicAdd(&g_slot1[slot], enc) + enc;
    if ((tot >> 44) == (unsigned long long)SLOT_QUOTA) {
        atomicExch(&g_slot1[slot], 0ULL);               // re-arm slot
        unsigned long long enc2 = (1ULL << 44) | (tot & MASK44);
        unsigned long long t2 = atomicAdd(&g_slot2, enc2) + enc2;
        if ((t2 >> 44) == (unsigned long long)SLOTS) {
            out[0] = (float)((double)(t2 & MASK44) * (1.0 / 4294967296.0));
            atomicExch(&g_slot2, 0ULL);                 // re-arm level 2
        }
    }
}

// ---------- single fused kernel: det + seg + hierarchical-atomic final ----------

__global__ __launch_bounds__(256) void fused_kernel(
        const float* __restrict__ seg_logits, const int* __restrict__ mask,
        const float* __restrict__ cls0, const float* __restrict__ cls1, const float* __restrict__ cls2,
        const float* __restrict__ reg0, const float* __restrict__ reg1, const float* __restrict__ reg2,
        const float* __restrict__ cen0, const float* __restrict__ cen1, const float* __restrict__ cen2,
        const float* __restrict__ boxes, const int* __restrict__ labels,
        const float* __restrict__ cls_pred, const int* __restrict__ cls_target,
        float* __restrict__ out) {

    if (blockIdx.x < DET_BLOCKS) {
        // ===== det block: one (scale, image) =====
        const int s = blockIdx.x >> 5;   // 0..2
        const int b = blockIdx.x & 31;   // 0..31
        int Wd, shift, L; float stride;
        const float *cls, *reg, *cen;
        if (s == 0)      { Wd = 64; shift = 6; L = 4096; stride = 8.f;  cls = cls0; reg = reg0; cen = cen0; }
        else if (s == 1) { Wd = 32; shift = 5; L = 1024; stride = 16.f; cls = cls1; reg = reg1; cen = cen1; }
        else             { Wd = 16; shift = 4; L = 256;  stride = 32.f; cls = cls2; reg = reg2; cen = cen2; }

        __shared__ float sx0[20], sy0[20], sx1[20], sy1[20], sar[20];
        __shared__ int   slb[20];
        if (threadIdx.x < 20) {
            int k = threadIdx.x;
            const float* bb = boxes + (b * 20 + k) * 4;
            float cx = bb[0] * 512.f, cy = bb[1] * 512.f;
            float w  = bb[2] * 512.f, h  = bb[3] * 512.f;
            float x0 = cx - 0.5f * w, y0 = cy - 0.5f * h;
            float x1 = cx + 0.5f * w, y1 = cy + 0.5f * h;
            sx0[k] = x0; sy0[k] = y0; sx1[k] = x1; sy1[k] = y1;
            sar[k] = (x1 - x0) * (y1 - y0);
            slb[k] = labels[b * 20 + k];
        }
        __syncthreads();

        const float* clsb = cls + (size_t)b * 5 * L;
        const float* regb = reg + (size_t)b * 4 * L;
        const float* cenb = cen + (size_t)b * L;
        const float inv = 1.f / stride;

        float cls_s = 0.f, reg_s = 0.f, cen_s = 0.f, np = 0.f, clsp = 0.f;
        // fold the W_CLS focal term into the lightest det blocks (s==2, L=256):
        // threads 0..9 handle image b's 10 class logits.
        if (s == 2 && threadIdx.x < 10) {
            clsp = focal_elt(cls_pred[b * 10 + threadIdx.x],
                             (cls_target[b] == (int)threadIdx.x) ? 1.f : 0.f);
        }
        for (int l = threadIdx.x; l < L; l += 256) {
            float lx = ((l & (Wd - 1)) + 0.5f) * stride;
            float ly = ((l >> shift)   + 0.5f) * stride;
            int bk = -1; float ba = INFINITY;
            float bl = 0.f, btp = 0.f, brr = 0.f, bbt = 0.f;
#pragma unroll
            for (int k = 0; k < 20; k++) {
                float li = lx - sx0[k], ti = ly - sy0[k];
                float ri = sx1[k] - lx, bi = sy1[k] - ly;
                float mn = fminf(fminf(li, ti), fminf(ri, bi));
                if (mn > 0.f && sar[k] < ba) {   // strict '<' == first-occurrence argmin
                    ba = sar[k]; bk = k;
                    bl = li; btp = ti; brr = ri; bbt = bi;
                }
            }
            int tl = (bk >= 0) ? slb[bk] : -1;
#pragma unroll
            for (int c = 0; c < 4; c++) {
                float x = clsb[(c + 1) * L + l];   // channel 0 dropped by reference
                cls_s += focal_elt(x, (c == tl) ? 1.f : 0.f);
            }
            if (bk >= 0) {
                float r0 = bl * inv, r1 = btp * inv, r2 = brr * inv, r3 = bbt * inv;
                float d0 = regb[0 * L + l] - r0;
                float d1 = regb[1 * L + l] - r1;
                float d2 = regb[2 * L + l] - r2;
                float d3 = regb[3 * L + l] - r3;
                float a0 = fabsf(d0), a1 = fabsf(d1), a2 = fabsf(d2), a3 = fabsf(d3);
                float sl = (a0 < 1.f ? 0.5f * d0 * d0 : a0 - 0.5f)
                         + (a1 < 1.f ? 0.5f * d1 * d1 : a1 - 0.5f)
                         + (a2 < 1.f ? 0.5f * d2 * d2 : a2 - 0.5f)
                         + (a3 < 1.f ? 0.5f * d3 * d3 : a3 - 0.5f);
                reg_s += 0.25f * sl;
                float mnlr = fminf(r0, r2), mxlr = fmaxf(r0, r2);
                float mntb = fminf(r1, r3), mxtb = fmaxf(r1, r3);
                float v = (mnlr / (mxlr + 1e-6f)) * (mntb / (mxtb + 1e-6f));
                v = fminf(fmaxf(v, 0.f), 1.f);
                float ct = sqrtf(v);
                cen_s += bce_logits(cenb[l], ct);
                np += 1.f;
            }
        }

        float v5[5] = {cls_s, reg_s, cen_s, np, clsp};
        blk_reduce_arr<5>(v5);
        if (threadIdx.x == 0) {
            float cls_l = v5[0] / (L * 4.f);
            float npos  = v5[3];
            float denom = fmaxf(npos, 1.f);
            float reg_l = (npos > 0.f) ? v5[1] / denom : 0.f;
            float cen_l = (npos > 0.f) ? v5[2] / denom : 0.f;
            float partial = (cls_l + reg_l + cen_l) * (1.f / (float)DET_BLOCKS)
                          + v5[4] * (0.5f / 320.f);   // W_CLS / (B*10)
            emit_partial(partial, out);
        }
        return;
    }

    // ===== seg block: mask-in-registers, 4 contiguous channel sweeps =====
    // (r6 structure: minimum logical bytes, no LDS, no syncs. The far-memory
    // read rate is pinned at ~2.1 TB/s by per-CU line-fill concurrency --
    // invariant across 7 tested structures -- so this phase is at its floor.)
    const int s = blockIdx.x - DET_BLOCKS;   // 0..1023
    const int b = s >> 5;                    // image
    const int k = s & 31;                    // 32-KB chunk within image
    const int t = threadIdx.x;

    const intx4*   Mq = (const intx4*)mask + (size_t)b * 65536 + k * 2048;
    const floatx4* Lq = (const floatx4*)seg_logits + (size_t)b * 262144 + k * 2048;

    // mask -> registers, convert once (reused by all 4 channels)
    intx4 mr[8];
#pragma unroll
    for (int j = 0; j < 8; j++) mr[j] = Mq[j * 256 + t];
    float mf[8][4];
#pragma unroll
    for (int j = 0; j < 8; j++) {
        mf[j][0] = (float)mr[j].x; mf[j][1] = (float)mr[j].y;
        mf[j][2] = (float)mr[j].z; mf[j][3] = (float)mr[j].w;
    }

    float acc = 0.f;
#pragma unroll
    for (int c = 0; c < 4; c++) {
#pragma unroll
        for (int j = 0; j < 8; j++) {
            const floatx4 x = Lq[c * 65536 + j * 256 + t];
            acc += bce_logits(x.x, mf[j][0]) + bce_logits(x.y, mf[j][1])
                 + bce_logits(x.z, mf[j][2]) + bce_logits(x.w, mf[j][3]);
        }
    }

    float v[1] = {acc};
    blk_reduce_arr<1>(v);
    if (threadIdx.x == 0) {
        emit_partial(v[0] * (1.f / 33554432.f), out);   // / B*4*512*512
    }
}

// ---------- launch: single dispatch ----------

extern "C" void kernel_launch(void* const* d_in, const int* in_sizes, int n_in,
                              void* d_out, int out_size, void* d_ws, size_t ws_size,
                              hipStream_t stream) {
    const float* seg_logits = (const float*)d_in[0];
    const int*   seg_mask   = (const int*)d_in[1];
    const float* cls0 = (const float*)d_in[2];
    const float* cls1 = (const float*)d_in[3];
    const float* cls2 = (const float*)d_in[4];
    const float* reg0 = (const float*)d_in[5];
    const float* reg1 = (const float*)d_in[6];
    const float* reg2 = (const float*)d_in[7];
    const float* cen0 = (const float*)d_in[8];
    const float* cen1 = (const float*)d_in[9];
    const float* cen2 = (const float*)d_in[10];
    const float* boxes  = (const float*)d_in[11];
    const int*   labels = (const int*)d_in[12];
    const float* cls_pred   = (const float*)d_in[13];
    const int*   cls_target = (const int*)d_in[14];

    fused_kernel<<<TOTAL_BLOCKS, 256, 0, stream>>>(seg_logits, seg_mask,
                                                   cls0, cls1, cls2,
                                                   reg0, reg1, reg2,
                                                   cen0, cen1, cen2,
                                                   boxes, labels,
                                                   cls_pred, cls_target,
                                                   (float*)d_out);
}